// Round 2
// baseline (28.224 us; speedup 1.0000x reference)
//
#include <hip/hip_runtime.h>
#include <math.h>

// Problem constants (match reference)
#define NDT   9
#define NT    2160      // forcing steps == NFORCING
#define NSUB  60
#define FC_F  1e-4f
#define DT_F  60.0f

#define BLK   1024
#define NW    (BLK / 64)   // 16 waves
#define CH    3            // hours per thread in scan (2160 = 720*3)

// jnp.gradient along axis 0 with spacing DT=60 (reference quirk), f32
__device__ __forceinline__ float grad_at(const float* __restrict__ X, int i) {
  if (i == 0)      return (X[1]      - X[0])      * (1.0f / 60.0f);
  if (i == NT - 1) return (X[NT - 1] - X[NT - 2]) * (1.0f / 60.0f);
  return (X[i + 1] - X[i - 1]) * (1.0f / 120.0f);
}

__global__ __launch_bounds__(BLK) void fused_slab_kernel(
    const float* __restrict__ pk,
    const float* __restrict__ TAx,
    const float* __restrict__ TAy,
    float* __restrict__ out) {
  __shared__ float  sKt1[NT];
  __shared__ float  sUe[NT];
  __shared__ float  sVe[NT];
  __shared__ float4 sHc[NT];       // per-hour composite: Cr,Ci,Dr,Di (f32)
  __shared__ double sW[NW][4];     // wave inclusive totals
  __shared__ double sWo[NW][4];    // inclusive scan of wave totals
  __shared__ float  sEK[2 * NDT];  // exp(pk)

  const int tid  = threadIdx.x;
  const int lane = tid & 63;
  const int wid  = tid >> 6;

  if (tid < 2 * NDT) sEK[tid] = expf(pk[tid]);
  __syncthreads();

  // ---------- phase 1: Kt1, Ue, Ve per forcing step (f32) ----------
  for (int t = tid; t < NT; t += BLK) {
    float gt = (float)t * (1.0f / 240.0f);  // (t*3600)/864000
    float S = 0.0f, a0 = 0.0f, a1 = 0.0f;
#pragma unroll
    for (int j = 0; j < NDT; ++j) {
      float d = gt - (float)j;
      float w = expf(-0.5f * d * d);
      S  += w;
      a0 += w * sEK[2 * j];
      a1 += w * sEK[2 * j + 1];
    }
    float k0 = a0 / S, k1 = a1 / S;
    float tax = TAx[t], tay = TAy[t];
    float den = k1 * k1 + FC_F * FC_F;
    float s = k0 / den;
    sKt1[t] = k1;
    sUe[t] = s * (tax * k1 + tay * FC_F);   // Re(Ce)
    sVe[t] = s * (tay * k1 - tax * FC_F);   // Im(Ce)
  }
  __syncthreads();

  // ---------- phase 2: per-hour affine composite (f32) ----------
  // Substep map: W <- c_i*W + d_i, c_i = (1-60*kt_i) + i*(-0.006),
  // d_i = P + Q*fi (linear in substep index). Composite:
  //   C = prod c_i ; D = P*T0 + Q*T1, T0 = sum S_i, T1 = sum i*S_i,
  // where S_i = suffix product (computed by descending-i recurrence).
  const float ci = -DT_F * FC_F;  // -0.006
  for (int h = tid; h < NT; h += BLK) {
    int itsup = (h + 1 >= NT) ? (NT - 1) : (h + 1);  // jnp -1 wrap
    float dUa = grad_at(sUe, h), dUb = grad_at(sUe, itsup);
    float dVa = grad_at(sVe, h), dVb = grad_at(sVe, itsup);
    float kB = sKt1[itsup];
    // d_i = -60*((1-i/60)dU a + (i/60)dUb) = (-60*dUa) + i*(dUa-dUb)
    float Pr = -DT_F * dUa, Qr = dUa - dUb;
    float Pi = -DT_F * dVa, Qi = dVa - dVb;

    float Sr = 1.0f, Si = 0.0f;
    float T0r = 0.0f, T0i = 0.0f, T1r = 0.0f, T1i = 0.0f;

    if (h >= 36) {
      // Kt[it-1] index clamps to NT-1 for every substep: kA constant
      float kA = sKt1[NT - 1];
      float A0 = 1.0f - DT_F * kA;   // a_i = A0 - (kB-kA)*i
      float sl = kB - kA;
      float fi = 59.0f;
      for (int i = 59; i >= 0; --i) {
        T0r += Sr; T0i += Si;
        T1r = fmaf(fi, Sr, T1r); T1i = fmaf(fi, Si, T1i);
        float a = A0 - sl * fi;
        float nSr = a * Sr - ci * Si;
        float nSi = a * Si + ci * Sr;
        Sr = nSr; Si = nSi;
        fi -= 1.0f;
      }
    } else {
      // general path: kA = Kt1[it-1] varies per substep (wrap at -1)
      float fi = 59.0f;
      for (int i = 59; i >= 0; --i) {
        T0r += Sr; T0i += Si;
        T1r = fmaf(fi, Sr, T1r); T1i = fmaf(fi, Si, T1i);
        int idx = h * NSUB + i - 1;
        if (idx < 0) idx = NT - 1;     // JAX wraps negative index
        float kA = sKt1[idx];
        float aa = fi * (1.0f / 60.0f);
        float kt = kA + (kB - kA) * aa;
        float a = 1.0f - DT_F * kt;
        float nSr = a * Sr - ci * Si;
        float nSi = a * Si + ci * Sr;
        Sr = nSr; Si = nSi;
        fi -= 1.0f;
      }
    }
    // D = P*T0 + Q*T1 (complex)
    float Dr = (Pr * T0r - Pi * T0i) + (Qr * T1r - Qi * T1i);
    float Di = (Pr * T0i + Pi * T0r) + (Qr * T1i + Qi * T1r);
    sHc[h] = make_float4(Sr, Si, Dr, Di);
  }
  __syncthreads();

  // ---------- phase 3: exclusive prefix scan (f64) + output ----------
  // Thread t owns hours [3t, 3t+3); 720 active threads, rest identity.
  double Cr = 1.0, Ci2 = 0.0, Dr = 0.0, Di = 0.0;
  int h0 = tid * CH;
  if (h0 < NT) {
    for (int m = 0; m < CH; ++m) {
      float4 e = sHc[h0 + m];
      double er = e.x, ei = e.y, fr = e.z, fi = e.w;
      double nCr = er * Cr - ei * Ci2;
      double nCi = er * Ci2 + ei * Cr;
      double nDr = er * Dr - ei * Di + fr;
      double nDi = er * Di + ei * Dr + fi;
      Cr = nCr; Ci2 = nCi; Dr = nDr; Di = nDi;
    }
  }
  // wave-level inclusive scan (compose current-after-partner)
  for (int s = 1; s < 64; s <<= 1) {
    double pCr = __shfl_up(Cr, s);
    double pCi = __shfl_up(Ci2, s);
    double pDr = __shfl_up(Dr, s);
    double pDi = __shfl_up(Di, s);
    if (lane >= s) {
      double nCr = Cr * pCr - Ci2 * pCi;
      double nCi = Cr * pCi + Ci2 * pCr;
      double nDr = Cr * pDr - Ci2 * pDi + Dr;
      double nDi = Cr * pDi + Ci2 * pDr + Di;
      Cr = nCr; Ci2 = nCi; Dr = nDr; Di = nDi;
    }
  }
  if (lane == 63) { sW[wid][0] = Cr; sW[wid][1] = Ci2; sW[wid][2] = Dr; sW[wid][3] = Di; }
  __syncthreads();

  if (wid == 0) {
    double wCr = 1.0, wCi = 0.0, wDr = 0.0, wDi = 0.0;
    if (lane < NW) { wCr = sW[lane][0]; wCi = sW[lane][1]; wDr = sW[lane][2]; wDi = sW[lane][3]; }
    for (int s = 1; s < NW; s <<= 1) {
      double pCr = __shfl_up(wCr, s);
      double pCi = __shfl_up(wCi, s);
      double pDr = __shfl_up(wDr, s);
      double pDi = __shfl_up(wDi, s);
      if (lane >= s && lane < NW) {
        double nCr = wCr * pCr - wCi * pCi;
        double nCi = wCr * pCi + wCi * pCr;
        double nDr = wCr * pDr - wCi * pDi + wDr;
        double nDi = wCr * pDi + wCi * pDr + wDi;
        wCr = nCr; wCi = nCi; wDr = nDr; wDi = nDi;
      }
    }
    if (lane < NW) { sWo[lane][0] = wCr; sWo[lane][1] = wCi; sWo[lane][2] = wDr; sWo[lane][3] = wDi; }
  }
  __syncthreads();

  // thread-exclusive prefix = laneExcl (later) ∘ waveExcl (earlier)
  double lCr = __shfl_up(Cr, 1), lCi = __shfl_up(Ci2, 1);
  double lDr = __shfl_up(Dr, 1), lDi = __shfl_up(Di, 1);
  if (lane == 0) { lCr = 1.0; lCi = 0.0; lDr = 0.0; lDi = 0.0; }
  double wCr = 1.0, wCi = 0.0, wDr = 0.0, wDi = 0.0;
  if (wid > 0) { wCr = sWo[wid - 1][0]; wCi = sWo[wid - 1][1]; wDr = sWo[wid - 1][2]; wDi = sWo[wid - 1][3]; }
  double rCr = lCr * wCr - lCi * wCi;
  double rCi = lCr * wCi + lCi * wCr;
  double rDr = lCr * wDr - lCi * wDi + lDr;
  double rDi = lCr * wDi + lCi * wDr + lDi;

  if (h0 < NT) {
    for (int m = 0; m < CH; ++m) {
      int h = h0 + m;
      out[h]      = (float)((double)sUe[h] + rDr);
      out[NT + h] = (float)((double)sVe[h] + rDi);
      float4 e = sHc[h];
      double er = e.x, ei = e.y, fr = e.z, fi = e.w;
      double nCr = er * rCr - ei * rCi;
      double nCi = er * rCi + ei * rCr;
      double nDr = er * rDr - ei * rDi + fr;
      double nDi = er * rDi + ei * rDr + fi;
      rCr = nCr; rCi = nCi; rDr = nDr; rDi = nDi;
    }
  }
}

// ---------------------------------------------------------------------------
extern "C" void kernel_launch(void* const* d_in, const int* in_sizes, int n_in,
                              void* d_out, int out_size, void* d_ws, size_t ws_size,
                              hipStream_t stream) {
  const float* pk  = (const float*)d_in[0];
  const float* TAx = (const float*)d_in[1];
  const float* TAy = (const float*)d_in[2];
  float* out = (float*)d_out;
  fused_slab_kernel<<<1, BLK, 0, stream>>>(pk, TAx, TAy, out);
}

// Round 3
// 17.819 us; speedup vs baseline: 1.5839x; 1.5839x over previous
//
#include <hip/hip_runtime.h>
#include <math.h>

// Problem constants (match reference)
#define NDT   9
#define NT    2160      // forcing steps == NFORCING
#define NSUB  60
#define FC_F  1e-4f
#define DT_F  60.0f

#define BT     512                 // threads per block (8 waves)
#define NWAVES (BT / 64)
#define W_OUT  128                 // output hours per block
#define L_TAIL 512                 // truncated history (|C|^512 < 2e-5 worst case)
#define WMAX   (W_OUT + L_TAIL)    // 640 max window hours
#define NBLK   ((NT + W_OUT - 1) / W_OUT)   // 17
#define CH     2                   // scan window elems per thread (2*512 >= 640)

// jnp.gradient (spacing 60, the reference quirk) on an LDS slice; i absolute,
// slice holds X[lo .. hi].
__device__ __forceinline__ float gradw(const float* __restrict__ X, int i, int lo) {
  if (i == 0)      return (X[1 - lo]      - X[0 - lo])      * (1.0f / 60.0f);
  if (i == NT - 1) return (X[NT - 1 - lo] - X[NT - 2 - lo]) * (1.0f / 60.0f);
  return (X[i + 1 - lo] - X[i - 1 - lo]) * (1.0f / 120.0f);
}

__device__ __forceinline__ void kt_row(int t, const float* __restrict__ sEK,
                                       float& k0, float& k1) {
  float gt = (float)t * (1.0f / 240.0f);  // (t*3600)/864000
  float S = 0.0f, a0 = 0.0f, a1 = 0.0f;
#pragma unroll
  for (int j = 0; j < NDT; ++j) {
    float d = gt - (float)j;
    float w = expf(-0.5f * d * d);
    S  += w;
    a0 += w * sEK[2 * j];
    a1 += w * sEK[2 * j + 1];
  }
  k0 = a0 / S; k1 = a1 / S;
}

__global__ __launch_bounds__(BT) void fused_slab_kernel(
    const float* __restrict__ pk,
    const float* __restrict__ TAx,
    const float* __restrict__ TAy,
    float* __restrict__ out) {
  __shared__ float  sKt1[NT];          // absolute-indexed
  __shared__ float  sUe[WMAX + 3];     // window slice, index t - ulo
  __shared__ float  sVe[WMAX + 3];
  __shared__ float4 sHc[WMAX];         // per-hour composite Cr,Ci,Dr,Di (f32)
  __shared__ double sW[NWAVES][4];     // wave inclusive totals (f64)
  __shared__ float  sEK[2 * NDT];

  const int tid  = threadIdx.x;
  const int lane = tid & 63;
  const int wid  = tid >> 6;
  const int b    = blockIdx.x;

  const int out0 = b * W_OUT;
  const int ws_  = (out0 - L_TAIL > 0) ? (out0 - L_TAIL) : 0;
  const int we_  = (out0 + W_OUT < NT) ? (out0 + W_OUT) : NT;
  const int wlen = we_ - ws_;
  const int ulo  = (ws_ - 1 > 0) ? (ws_ - 1) : 0;
  const int uhi  = (we_ + 1 < NT - 1) ? (we_ + 1) : (NT - 1);
  const bool slow = (ws_ == 0);        // window contains hours < 36

  if (tid < 2 * NDT) sEK[tid] = expf(pk[tid]);
  __syncthreads();

  // ---------- phase A: Kt1 / Ue / Ve for this block's needs ----------
  if (slow) {
    // need full Kt1 (fine-grained indices for hours < 36)
    for (int t = tid; t < NT; t += BT) {
      float k0, k1; kt_row(t, sEK, k0, k1);
      sKt1[t] = k1;
      if (t >= ulo && t <= uhi) {
        float tax = TAx[t], tay = TAy[t];
        float den = k1 * k1 + FC_F * FC_F;
        float s = k0 / den;
        sUe[t - ulo] = s * (tax * k1 + tay * FC_F);
        sVe[t - ulo] = s * (tay * k1 - tax * FC_F);
      }
    }
  } else {
    for (int t = ulo + tid; t <= uhi; t += BT) {
      float k0, k1; kt_row(t, sEK, k0, k1);
      sKt1[t] = k1;
      float tax = TAx[t], tay = TAy[t];
      float den = k1 * k1 + FC_F * FC_F;
      float s = k0 / den;
      sUe[t - ulo] = s * (tax * k1 + tay * FC_F);
      sVe[t - ulo] = s * (tay * k1 - tax * FC_F);
    }
    if (tid == 0 && uhi < NT - 1) {   // fast-path kA = Kt1[NT-1]
      float k0, k1; kt_row(NT - 1, sEK, k0, k1);
      sKt1[NT - 1] = k1;
    }
  }
  __syncthreads();

  // ---------- phase B: per-hour affine composites (f32) ----------
  // Substep: W <- c_i*W + d_i ; C = prod c_i ; D = P*T0 + Q*T1 with
  // T0 = sum S_i, T1 = sum i*S_i, S_i = suffix product (descending i).
  const float ci = -DT_F * FC_F;  // -0.006
  for (int p = tid; p < wlen; p += BT) {
    int h = ws_ + p;
    int itsup = (h + 1 >= NT) ? (NT - 1) : (h + 1);   // jnp -1 wrap
    float dUa = gradw(sUe, h, ulo), dUb = gradw(sUe, itsup, ulo);
    float dVa = gradw(sVe, h, ulo), dVb = gradw(sVe, itsup, ulo);
    float kB = sKt1[itsup];
    float Pr = -DT_F * dUa, Qr = dUa - dUb;
    float Pi = -DT_F * dVa, Qi = dVa - dVb;

    float Sr = 1.0f, Si = 0.0f;
    float T0r = 0.0f, T0i = 0.0f, T1r = 0.0f, T1i = 0.0f;

    if (h >= 36) {
      // Kt[it-1] clamps to NT-1 for every substep
      float kA = sKt1[NT - 1];
      float A0 = 1.0f - DT_F * kA;
      float sl = kB - kA;
      float fi = 59.0f;
#pragma unroll 10
      for (int i = 59; i >= 0; --i) {
        T0r += Sr; T0i += Si;
        T1r = fmaf(fi, Sr, T1r); T1i = fmaf(fi, Si, T1i);
        float a = A0 - sl * fi;
        float nSr = a * Sr - ci * Si;
        float nSi = a * Si + ci * Sr;
        Sr = nSr; Si = nSi;
        fi -= 1.0f;
      }
    } else {
      float fi = 59.0f;
#pragma unroll 10
      for (int i = 59; i >= 0; --i) {
        T0r += Sr; T0i += Si;
        T1r = fmaf(fi, Sr, T1r); T1i = fmaf(fi, Si, T1i);
        int idx = h * NSUB + i - 1;
        if (idx < 0) idx = NT - 1;      // JAX wraps -1
        float kA = sKt1[idx];
        float aa = fi * (1.0f / 60.0f);
        float kt = kA + (kB - kA) * aa;
        float a = 1.0f - DT_F * kt;
        float nSr = a * Sr - ci * Si;
        float nSi = a * Si + ci * Sr;
        Sr = nSr; Si = nSi;
        fi -= 1.0f;
      }
    }
    float Dr = (Pr * T0r - Pi * T0i) + (Qr * T1r - Qi * T1i);
    float Di = (Pr * T0i + Pi * T0r) + (Qr * T1i + Qi * T1r);
    sHc[p] = make_float4(Sr, Si, Dr, Di);
  }
  __syncthreads();

  // ---------- phase C: in-block exclusive scan (f64) + output ----------
  // Thread owns window positions [CH*tid, CH*tid+CH).
  double Cr = 1.0, Ci2 = 0.0, Dr = 0.0, Di = 0.0;
  int p0 = tid * CH;
  for (int m = 0; m < CH; ++m) {
    int p = p0 + m;
    if (p >= wlen) break;
    float4 e = sHc[p];
    double er = e.x, ei = e.y, fr = e.z, fi = e.w;
    double nCr = er * Cr - ei * Ci2;
    double nCi = er * Ci2 + ei * Cr;
    double nDr = er * Dr - ei * Di + fr;
    double nDi = er * Di + ei * Dr + fi;
    Cr = nCr; Ci2 = nCi; Dr = nDr; Di = nDi;
  }
  // wave inclusive scan (compose current-after-partner)
  for (int s = 1; s < 64; s <<= 1) {
    double pCr = __shfl_up(Cr, s);
    double pCi = __shfl_up(Ci2, s);
    double pDr = __shfl_up(Dr, s);
    double pDi = __shfl_up(Di, s);
    if (lane >= s) {
      double nCr = Cr * pCr - Ci2 * pCi;
      double nCi = Cr * pCi + Ci2 * pCr;
      double nDr = Cr * pDr - Ci2 * pDi + Dr;
      double nDi = Cr * pDi + Ci2 * pDr + Di;
      Cr = nCr; Ci2 = nCi; Dr = nDr; Di = nDi;
    }
  }
  if (lane == 63) { sW[wid][0] = Cr; sW[wid][1] = Ci2; sW[wid][2] = Dr; sW[wid][3] = Di; }
  __syncthreads();

  // wave-exclusive prefix: compose earlier waves' totals serially (wid <= 7)
  double wCr = 1.0, wCi = 0.0, wDr = 0.0, wDi = 0.0;
  for (int w = 0; w < wid; ++w) {
    double er = sW[w][0], ei = sW[w][1], fr = sW[w][2], fi = sW[w][3];
    // apply wave w (later) after acc (earlier)
    double nCr = er * wCr - ei * wCi;
    double nCi = er * wCi + ei * wCr;
    double nDr = er * wDr - ei * wDi + fr;
    double nDi = er * wDi + ei * wDr + fi;
    wCr = nCr; wCi = nCi; wDr = nDr; wDi = nDi;
  }
  // lane-exclusive within wave
  double lCr = __shfl_up(Cr, 1), lCi = __shfl_up(Ci2, 1);
  double lDr = __shfl_up(Dr, 1), lDi = __shfl_up(Di, 1);
  if (lane == 0) { lCr = 1.0; lCi = 0.0; lDr = 0.0; lDi = 0.0; }
  // threadExcl = laneExcl (later) ∘ waveExcl (earlier)
  double rCr = lCr * wCr - lCi * wCi;
  double rCi = lCr * wCi + lCi * wCr;
  double rDr = lCr * wDr - lCi * wDi + lDr;
  double rDi = lCr * wDi + lCi * wDr + lDi;

  // walk owned positions; write outputs for h >= out0
  for (int m = 0; m < CH; ++m) {
    int p = p0 + m;
    if (p >= wlen) break;
    int h = ws_ + p;
    if (h >= out0) {
      out[h]      = (float)((double)sUe[h - ulo] + rDr);
      out[NT + h] = (float)((double)sVe[h - ulo] + rDi);
    }
    float4 e = sHc[p];
    double er = e.x, ei = e.y, fr = e.z, fi = e.w;
    double nCr = er * rCr - ei * rCi;
    double nCi = er * rCi + ei * rCr;
    double nDr = er * rDr - ei * rDi + fr;
    double nDi = er * rDi + ei * rDr + fi;
    rCr = nCr; rCi = nCi; rDr = nDr; rDi = nDi;
  }
}

// ---------------------------------------------------------------------------
extern "C" void kernel_launch(void* const* d_in, const int* in_sizes, int n_in,
                              void* d_out, int out_size, void* d_ws, size_t ws_size,
                              hipStream_t stream) {
  const float* pk  = (const float*)d_in[0];
  const float* TAx = (const float*)d_in[1];
  const float* TAy = (const float*)d_in[2];
  float* out = (float*)d_out;
  fused_slab_kernel<<<NBLK, BT, 0, stream>>>(pk, TAx, TAy, out);
}

// Round 4
// 13.532 us; speedup vs baseline: 2.0858x; 1.3169x over previous
//
#include <hip/hip_runtime.h>
#include <math.h>

// Problem constants (match reference)
#define NDT   9
#define NT    2160      // forcing steps == NFORCING
#define NSUB  60
#define FC_F  1e-4f
#define DT_F  60.0f

#define BT     512                 // threads per block (8 waves)
#define NWAVES (BT / 64)
#define W_OUT  128                 // output hours per block
#define L_TAIL 320                 // truncated history: err ~1e-7 << 6.6e-6
#define WMAX   (W_OUT + L_TAIL)    // 448 <= BT -> one window elem per thread
#define NBLK   ((NT + W_OUT - 1) / W_OUT)   // 17

// jnp.gradient (spacing 60, reference quirk) on LDS slice; i absolute.
__device__ __forceinline__ float gradw(const float* __restrict__ X, int i, int lo) {
  if (i == 0)      return (X[1 - lo]      - X[0 - lo])      * (1.0f / 60.0f);
  if (i == NT - 1) return (X[NT - 1 - lo] - X[NT - 2 - lo]) * (1.0f / 60.0f);
  return (X[i + 1 - lo] - X[i - 1 - lo]) * (1.0f / 120.0f);
}

// Gaussian-basis row via ratio recurrence: only 2 expf instead of 9.
// w_j = exp(-0.5*(gt-j)^2); w_{j+1} = w_j * e^{gt-0.5} * e^{-j}.
// Common-factor rounding cancels in the a/S normalization.
__device__ __forceinline__ void kt_row(int t, const float* __restrict__ sEK,
                                       float& k0, float& k1) {
  float gt = (float)t * (1.0f / 240.0f);  // (t*3600)/864000
  float w = expf(-0.5f * gt * gt);        // j = 0
  float r = expf(gt - 0.5f);
  float S = w, a0 = w * sEK[0], a1 = w * sEK[1];
  const float E[8] = {1.0f, 0.36787944f, 0.13533528f, 0.049787068f,
                      0.018315639f, 0.0067379470f, 0.0024787522f, 0.00091188197f};
#pragma unroll
  for (int j = 0; j < 8; ++j) {
    w *= r * E[j];
    S += w;
    a0 = fmaf(w, sEK[2 * (j + 1)],     a0);
    a1 = fmaf(w, sEK[2 * (j + 1) + 1], a1);
  }
  k0 = a0 / S; k1 = a1 / S;
}

__global__ __launch_bounds__(BT) void fused_slab_kernel(
    const float* __restrict__ pk,
    const float* __restrict__ TAx,
    const float* __restrict__ TAy,
    float* __restrict__ out) {
  __shared__ float  sKt1[NT];          // absolute-indexed
  __shared__ float  sUe[WMAX + 3];     // window slice, index t - ulo
  __shared__ float  sVe[WMAX + 3];
  __shared__ float4 sHc[WMAX];         // per-hour composite Cr,Ci,Dr,Di (f32)
  __shared__ double sW[NWAVES][4];     // wave inclusive totals (f64)
  __shared__ float  sEK[2 * NDT];

  const int tid  = threadIdx.x;
  const int lane = tid & 63;
  const int wid  = tid >> 6;
  const int b    = blockIdx.x;

  const int out0 = b * W_OUT;
  const int ws_  = (out0 - L_TAIL > 0) ? (out0 - L_TAIL) : 0;
  const int we_  = (out0 + W_OUT < NT) ? (out0 + W_OUT) : NT;
  const int wlen = we_ - ws_;
  const int ulo  = (ws_ - 1 > 0) ? (ws_ - 1) : 0;
  const int uhi  = (we_ + 1 < NT - 1) ? (we_ + 1) : (NT - 1);
  const bool slow = (ws_ == 0);        // window contains hours < 36

  if (tid < 2 * NDT) sEK[tid] = expf(pk[tid]);
  __syncthreads();

  // ---------- phase A: Kt1 / Ue / Ve ----------
  if (slow) {
    for (int t = tid; t < NT; t += BT) {
      float k0, k1; kt_row(t, sEK, k0, k1);
      sKt1[t] = k1;
      if (t >= ulo && t <= uhi) {
        float tax = TAx[t], tay = TAy[t];
        float den = k1 * k1 + FC_F * FC_F;
        float s = k0 / den;
        sUe[t - ulo] = s * (tax * k1 + tay * FC_F);
        sVe[t - ulo] = s * (tay * k1 - tax * FC_F);
      }
    }
  } else {
    int t = ulo + tid;
    if (t <= uhi) {
      float k0, k1; kt_row(t, sEK, k0, k1);
      sKt1[t] = k1;
      float tax = TAx[t], tay = TAy[t];
      float den = k1 * k1 + FC_F * FC_F;
      float s = k0 / den;
      sUe[t - ulo] = s * (tax * k1 + tay * FC_F);
      sVe[t - ulo] = s * (tay * k1 - tax * FC_F);
    }
    if (tid == 0 && uhi < NT - 1) {    // fast-path kA source
      float k0, k1; kt_row(NT - 1, sEK, k0, k1);
      sKt1[NT - 1] = k1;
    }
  }
  __syncthreads();

  // ---------- phase B: per-hour affine composite, 4-way ILP ----------
  // Substep i: W <- c_i*W + d_i, c_i = a_i + i*ci (ci = -0.006 const),
  // a_i = 1 - (60-i)*kA_i - i*kB, d_i = P + Q*i.
  // Need C = prod c_i, T0 = sum_i S_i, T1 = sum_i i*S_i (S_i = suffix prod).
  // Split i into 4 chunks of 15 -> independent recurrences (ILP), combine.
  const float ci = -DT_F * FC_F;  // -0.006
  if (tid < wlen) {
    const int h = ws_ + tid;
    const int itsup = (h + 1 >= NT) ? (NT - 1) : (h + 1);   // jnp -1 wrap
    const float dUa = gradw(sUe, h, ulo), dUb = gradw(sUe, itsup, ulo);
    const float dVa = gradw(sVe, h, ulo), dVb = gradw(sVe, itsup, ulo);
    const float kB = sKt1[itsup];
    const float Pr = -DT_F * dUa, Qr = dUa - dUb;
    const float Pi = -DT_F * dVa, Qi = dVa - dVb;

    float Sr[4]  = {1.f, 1.f, 1.f, 1.f}, Si_[4] = {0.f, 0.f, 0.f, 0.f};
    float T0r[4] = {0.f}, T0i[4] = {0.f}, T1r[4] = {0.f}, T1i[4] = {0.f};
    const int base = h * NSUB - 1;

#pragma unroll 5
    for (int il = 14; il >= 0; --il) {
#pragma unroll
      for (int m = 0; m < 4; ++m) {
        const int i = 15 * m + il;
        const float fi = (float)i;
        // accumulate with current suffix product (covers j > i)
        T0r[m] += Sr[m]; T0i[m] += Si_[m];
        T1r[m] = fmaf(fi, Sr[m], T1r[m]); T1i[m] = fmaf(fi, Si_[m], T1i[m]);
        int idx = base + i;
        idx = (idx < 0 || idx > NT - 1) ? (NT - 1) : idx;  // JAX wrap/clamp
        const float kA = sKt1[idx];
        const float a = 1.0f - (60.0f - fi) * kA - fi * kB;
        const float nSr = a * Sr[m] - ci * Si_[m];
        const float nSi = a * Si_[m] + ci * Sr[m];
        Sr[m] = nSr; Si_[m] = nSi;
      }
    }
    // combine chunks (suffix order: m=3 outermost)
    float Mr = 1.0f, Mi = 0.0f;               // prod of chunks > m
    float T0cr = 0.0f, T0ci = 0.0f, T1cr = 0.0f, T1ci = 0.0f;
#pragma unroll
    for (int m = 3; m >= 0; --m) {
      T0cr += Mr * T0r[m] - Mi * T0i[m];
      T0ci += Mr * T0i[m] + Mi * T0r[m];
      T1cr += Mr * T1r[m] - Mi * T1i[m];
      T1ci += Mr * T1i[m] + Mi * T1r[m];
      const float nMr = Mr * Sr[m] - Mi * Si_[m];
      const float nMi = Mr * Si_[m] + Mi * Sr[m];
      Mr = nMr; Mi = nMi;
    }
    const float Dr = (Pr * T0cr - Pi * T0ci) + (Qr * T1cr - Qi * T1ci);
    const float Di = (Pr * T0ci + Pi * T0cr) + (Qr * T1ci + Qi * T1cr);
    sHc[tid] = make_float4(Mr, Mi, Dr, Di);   // (C, D) for this hour
  }
  __syncthreads();

  // ---------- phase C: exclusive prefix scan (f64), 1 elem/thread ----------
  double Cr = 1.0, Ci2 = 0.0, Dr = 0.0, Di = 0.0;
  if (tid < wlen) {
    float4 e = sHc[tid];
    Cr = e.x; Ci2 = e.y; Dr = e.z; Di = e.w;
  }
  for (int s = 1; s < 64; s <<= 1) {
    double pCr = __shfl_up(Cr, s);
    double pCi = __shfl_up(Ci2, s);
    double pDr = __shfl_up(Dr, s);
    double pDi = __shfl_up(Di, s);
    if (lane >= s) {
      double nCr = Cr * pCr - Ci2 * pCi;
      double nCi = Cr * pCi + Ci2 * pCr;
      double nDr = Cr * pDr - Ci2 * pDi + Dr;
      double nDi = Cr * pDi + Ci2 * pDr + Di;
      Cr = nCr; Ci2 = nCi; Dr = nDr; Di = nDi;
    }
  }
  if (lane == 63) { sW[wid][0] = Cr; sW[wid][1] = Ci2; sW[wid][2] = Dr; sW[wid][3] = Di; }
  __syncthreads();

  // wave-exclusive prefix: compose earlier waves serially (<= 7)
  double wCr = 1.0, wCi = 0.0, wDr = 0.0, wDi = 0.0;
  for (int w = 0; w < wid; ++w) {
    double er = sW[w][0], ei = sW[w][1], fr = sW[w][2], fi = sW[w][3];
    double nCr = er * wCr - ei * wCi;
    double nCi = er * wCi + ei * wCr;
    double nDr = er * wDr - ei * wDi + fr;
    double nDi = er * wDi + ei * wDr + fi;
    wCr = nCr; wCi = nCi; wDr = nDr; wDi = nDi;
  }
  double lCr = __shfl_up(Cr, 1), lCi = __shfl_up(Ci2, 1);
  double lDr = __shfl_up(Dr, 1), lDi = __shfl_up(Di, 1);
  if (lane == 0) { lCr = 1.0; lCi = 0.0; lDr = 0.0; lDi = 0.0; }
  // threadExcl = laneExcl (later) o waveExcl (earlier)
  double rDr = lCr * wDr - lCi * wDi + lDr;
  double rDi = lCr * wDi + lCi * wDr + lDi;

  if (tid < wlen) {
    int h = ws_ + tid;
    if (h >= out0) {
      out[h]      = (float)((double)sUe[h - ulo] + rDr);
      out[NT + h] = (float)((double)sVe[h - ulo] + rDi);
    }
  }
}

// ---------------------------------------------------------------------------
extern "C" void kernel_launch(void* const* d_in, const int* in_sizes, int n_in,
                              void* d_out, int out_size, void* d_ws, size_t ws_size,
                              hipStream_t stream) {
  const float* pk  = (const float*)d_in[0];
  const float* TAx = (const float*)d_in[1];
  const float* TAy = (const float*)d_in[2];
  float* out = (float*)d_out;
  fused_slab_kernel<<<NBLK, BT, 0, stream>>>(pk, TAx, TAy, out);
}

// Round 5
// 13.212 us; speedup vs baseline: 2.1363x; 1.0242x over previous
//
#include <hip/hip_runtime.h>
#include <math.h>

// Problem constants (match reference)
#define NDT   9
#define NT    2160      // forcing steps == NFORCING
#define NSUB  60
#define FC_F  1e-4f
#define DT_F  60.0f

#define BT     512                 // threads per block (8 waves)
#define NWAVES (BT / 64)
#define W_OUT  128                 // output hours per block
#define L_TAIL 320                 // truncated history: err ~1e-7 << 6.6e-6
#define WMAX   (W_OUT + L_TAIL)    // 448 <= BT -> one window elem per thread
#define NBLK   ((NT + W_OUT - 1) / W_OUT)   // 17
#define NKNOT  136                 // Kt1 knots at t=16j, j=0..135 (covers idx<=2159)

// jnp.gradient (spacing 60, reference quirk) on LDS slice; i absolute.
__device__ __forceinline__ float gradw(const float* __restrict__ X, int i, int lo) {
  if (i == 0)      return (X[1 - lo]      - X[0 - lo])      * (1.0f / 60.0f);
  if (i == NT - 1) return (X[NT - 1 - lo] - X[NT - 2 - lo]) * (1.0f / 60.0f);
  return (X[i + 1 - lo] - X[i - 1 - lo]) * (1.0f / 120.0f);
}

// Gaussian-basis row via ratio recurrence: 2 expf instead of 9.
// w_j = exp(-0.5*(gt-j)^2); w_{j+1} = w_j * e^{gt-0.5} * e^{-j}.
__device__ __forceinline__ void kt_row(int t, const float* __restrict__ sEK,
                                       float& k0, float& k1) {
  float gt = (float)t * (1.0f / 240.0f);  // (t*3600)/864000
  float w = expf(-0.5f * gt * gt);        // j = 0
  float r = expf(gt - 0.5f);
  float S = w, a0 = w * sEK[0], a1 = w * sEK[1];
  const float E[8] = {1.0f, 0.36787944f, 0.13533528f, 0.049787068f,
                      0.018315639f, 0.0067379470f, 0.0024787522f, 0.00091188197f};
#pragma unroll
  for (int j = 0; j < 8; ++j) {
    w *= r * E[j];
    S += w;
    a0 = fmaf(w, sEK[2 * (j + 1)],     a0);
    a1 = fmaf(w, sEK[2 * (j + 1) + 1], a1);
  }
  k0 = a0 / S; k1 = a1 / S;
}

__global__ __launch_bounds__(BT) void fused_slab_kernel(
    const float* __restrict__ pk,
    const float* __restrict__ TAx,
    const float* __restrict__ TAy,
    float* __restrict__ out) {
  __shared__ float  sKt1[NT];          // absolute-indexed; only window + [NT-1] used
  __shared__ float  sKnot[NKNOT];      // stride-16 Kt1 knots (slow blocks only)
  __shared__ float  sUe[WMAX + 3];     // window slice, index t - ulo
  __shared__ float  sVe[WMAX + 3];
  __shared__ float4 sHc[WMAX];         // per-hour composite Cr,Ci,Dr,Di (f32)
  __shared__ double sW[NWAVES][4];     // wave inclusive totals (f64)
  __shared__ float  sEK[2 * NDT];

  const int tid  = threadIdx.x;
  const int lane = tid & 63;
  const int wid  = tid >> 6;
  const int b    = blockIdx.x;

  const int out0 = b * W_OUT;
  const int ws_  = (out0 - L_TAIL > 0) ? (out0 - L_TAIL) : 0;
  const int we_  = (out0 + W_OUT < NT) ? (out0 + W_OUT) : NT;
  const int wlen = we_ - ws_;
  const int ulo  = (ws_ - 1 > 0) ? (ws_ - 1) : 0;
  const int uhi  = (we_ + 1 < NT - 1) ? (we_ + 1) : (NT - 1);
  const bool slow = (ws_ == 0);        // window contains hours < 36

  if (tid < 2 * NDT) sEK[tid] = expf(pk[tid]);
  __syncthreads();

  // ---------- phase A: window Kt1/Ue/Ve (1 round) + knots (slow) ----------
  {
    int t = ulo + tid;
    if (t <= uhi) {
      float k0, k1; kt_row(t, sEK, k0, k1);
      sKt1[t] = k1;
      float tax = TAx[t], tay = TAy[t];
      float den = k1 * k1 + FC_F * FC_F;
      float s = k0 / den;
      sUe[t - ulo] = s * (tax * k1 + tay * FC_F);
      sVe[t - ulo] = s * (tay * k1 - tax * FC_F);
    }
  }
  if (slow) {
    // 137 extra kt_rows in ONE parallel round: 136 knots + the Kt1[NT-1] clamp value
    if (tid < NKNOT) {
      float k0, k1; kt_row(16 * tid, sEK, k0, k1);
      sKnot[tid] = k1;
    } else if (tid == NKNOT) {
      float k0, k1; kt_row(NT - 1, sEK, k0, k1);
      sKt1[NT - 1] = k1;
    }
  } else if (tid == 0 && uhi < NT - 1) {
    float k0, k1; kt_row(NT - 1, sEK, k0, k1);
    sKt1[NT - 1] = k1;
  }
  __syncthreads();

  // ---------- phase B: per-hour affine composite, 4-way ILP ----------
  // Substep i: W <- c_i*W + d_i, c_i = a_i + i*ci (ci = -0.006 const),
  // a_i = 1 - (60-i)*kA_i - i*kB, d_i = P + Q*i.
  // C = prod c_i; T0 = sum S_i, T1 = sum i*S_i (S_i = suffix product).
  const float ci = -DT_F * FC_F;  // -0.006
  if (tid < wlen) {
    const int h = ws_ + tid;
    const int itsup = (h + 1 >= NT) ? (NT - 1) : (h + 1);   // jnp -1 wrap
    const float dUa = gradw(sUe, h, ulo), dUb = gradw(sUe, itsup, ulo);
    const float dVa = gradw(sVe, h, ulo), dVb = gradw(sVe, itsup, ulo);
    const float kB = sKt1[itsup];
    const float Pr = -DT_F * dUa, Qr = dUa - dUb;
    const float Pi = -DT_F * dVa, Qi = dVa - dVb;

    float Sr[4]  = {1.f, 1.f, 1.f, 1.f}, Si_[4] = {0.f, 0.f, 0.f, 0.f};
    float T0r[4] = {0.f}, T0i[4] = {0.f}, T1r[4] = {0.f}, T1i[4] = {0.f};

    if (h >= 36) {
      // Kt[it-1] clamps to NT-1 for every substep: constant kA
      const float kA = sKt1[NT - 1];
#pragma unroll 5
      for (int il = 14; il >= 0; --il) {
#pragma unroll
        for (int m = 0; m < 4; ++m) {
          const float fi = (float)(15 * m + il);
          T0r[m] += Sr[m]; T0i[m] += Si_[m];
          T1r[m] = fmaf(fi, Sr[m], T1r[m]); T1i[m] = fmaf(fi, Si_[m], T1i[m]);
          const float a = 1.0f - (60.0f - fi) * kA - fi * kB;
          const float nSr = a * Sr[m] - ci * Si_[m];
          const float nSi = a * Si_[m] + ci * Sr[m];
          Sr[m] = nSr; Si_[m] = nSi;
        }
      }
    } else {
      // fine-resolution kA via stride-16 knot lerp (abs err ~5e-9)
      const int base = h * NSUB - 1;
#pragma unroll 5
      for (int il = 14; il >= 0; --il) {
#pragma unroll
        for (int m = 0; m < 4; ++m) {
          const int i = 15 * m + il;
          const float fi = (float)i;
          T0r[m] += Sr[m]; T0i[m] += Si_[m];
          T1r[m] = fmaf(fi, Sr[m], T1r[m]); T1i[m] = fmaf(fi, Si_[m], T1i[m]);
          int idx = base + i;
          idx = (idx < 0 || idx > NT - 1) ? (NT - 1) : idx;  // JAX wrap/clamp
          const int j = idx >> 4;
          const float f = (float)(idx & 15) * 0.0625f;
          const float kj = sKnot[j];
          const float kA = fmaf(sKnot[j + 1] - kj, f, kj);
          const float a = 1.0f - (60.0f - fi) * kA - fi * kB;
          const float nSr = a * Sr[m] - ci * Si_[m];
          const float nSi = a * Si_[m] + ci * Sr[m];
          Sr[m] = nSr; Si_[m] = nSi;
        }
      }
    }
    // combine chunks (suffix order: m=3 outermost)
    float Mr = 1.0f, Mi = 0.0f;
    float T0cr = 0.0f, T0ci = 0.0f, T1cr = 0.0f, T1ci = 0.0f;
#pragma unroll
    for (int m = 3; m >= 0; --m) {
      T0cr += Mr * T0r[m] - Mi * T0i[m];
      T0ci += Mr * T0i[m] + Mi * T0r[m];
      T1cr += Mr * T1r[m] - Mi * T1i[m];
      T1ci += Mr * T1i[m] + Mi * T1r[m];
      const float nMr = Mr * Sr[m] - Mi * Si_[m];
      const float nMi = Mr * Si_[m] + Mi * Sr[m];
      Mr = nMr; Mi = nMi;
    }
    const float Dr = (Pr * T0cr - Pi * T0ci) + (Qr * T1cr - Qi * T1ci);
    const float Di = (Pr * T0ci + Pi * T0cr) + (Qr * T1ci + Qi * T1cr);
    sHc[tid] = make_float4(Mr, Mi, Dr, Di);
  }
  __syncthreads();

  // ---------- phase C: exclusive prefix scan (f64), 1 elem/thread ----------
  double Cr = 1.0, Ci2 = 0.0, Dr = 0.0, Di = 0.0;
  if (tid < wlen) {
    float4 e = sHc[tid];
    Cr = e.x; Ci2 = e.y; Dr = e.z; Di = e.w;
  }
  for (int s = 1; s < 64; s <<= 1) {
    double pCr = __shfl_up(Cr, s);
    double pCi = __shfl_up(Ci2, s);
    double pDr = __shfl_up(Dr, s);
    double pDi = __shfl_up(Di, s);
    if (lane >= s) {
      double nCr = Cr * pCr - Ci2 * pCi;
      double nCi = Cr * pCi + Ci2 * pCr;
      double nDr = Cr * pDr - Ci2 * pDi + Dr;
      double nDi = Cr * pDi + Ci2 * pDr + Di;
      Cr = nCr; Ci2 = nCi; Dr = nDr; Di = nDi;
    }
  }
  if (lane == 63) { sW[wid][0] = Cr; sW[wid][1] = Ci2; sW[wid][2] = Dr; sW[wid][3] = Di; }
  __syncthreads();

  // wave-exclusive prefix: compose earlier waves serially (<= 7)
  double wCr = 1.0, wCi = 0.0, wDr = 0.0, wDi = 0.0;
  for (int w = 0; w < wid; ++w) {
    double er = sW[w][0], ei = sW[w][1], fr = sW[w][2], fi = sW[w][3];
    double nCr = er * wCr - ei * wCi;
    double nCi = er * wCi + ei * wCr;
    double nDr = er * wDr - ei * wDi + fr;
    double nDi = er * wDi + ei * wDr + fi;
    wCr = nCr; wCi = nCi; wDr = nDr; wDi = nDi;
  }
  double lCr = __shfl_up(Cr, 1), lCi = __shfl_up(Ci2, 1);
  double lDr = __shfl_up(Dr, 1), lDi = __shfl_up(Di, 1);
  if (lane == 0) { lCr = 1.0; lCi = 0.0; lDr = 0.0; lDi = 0.0; }
  // threadExcl = laneExcl (later) o waveExcl (earlier); only D needed
  double rDr = lCr * wDr - lCi * wDi + lDr;
  double rDi = lCr * wDi + lCi * wDr + lDi;

  if (tid < wlen) {
    int h = ws_ + tid;
    if (h >= out0) {
      out[h]      = (float)((double)sUe[h - ulo] + rDr);
      out[NT + h] = (float)((double)sVe[h - ulo] + rDi);
    }
  }
}

// ---------------------------------------------------------------------------
extern "C" void kernel_launch(void* const* d_in, const int* in_sizes, int n_in,
                              void* d_out, int out_size, void* d_ws, size_t ws_size,
                              hipStream_t stream) {
  const float* pk  = (const float*)d_in[0];
  const float* TAx = (const float*)d_in[1];
  const float* TAy = (const float*)d_in[2];
  float* out = (float*)d_out;
  fused_slab_kernel<<<NBLK, BT, 0, stream>>>(pk, TAx, TAy, out);
}